// Round 19
// baseline (27.897 us; speedup 1.0000x reference)
//
#include <hip/hip_runtime.h>
#include <math.h>

// Problem constants
#define Dq 512
#define Vq 50257
#define Kq 100
#define KP 112              // K padded to 7*16
#define NORM_TERM 10.8249051f   // log(50257)
#define LOGK 4.6051702f         // log(100)
#define NBLK 512            // 16384 positions / 32 per block
#define DT_STRIDE 3584      // nBT: KP*32 elems per d-chunk slab (7KB, non-pow2)

typedef __attribute__((ext_vector_type(8))) short short8;
typedef __attribute__((ext_vector_type(4))) float floatx4;
typedef __attribute__((ext_vector_type(4))) unsigned short ushort4v;
typedef __attribute__((ext_vector_type(8))) unsigned short ushort8v;

__device__ __forceinline__ unsigned short f2bf(float f) {
    union { float f; unsigned u; } v; v.f = f;
    unsigned r = v.u + 0x7FFFu + ((v.u >> 16) & 1u);   // RNE
    return (unsigned short)(r >> 16);
}

__device__ __forceinline__ short8 cvt8(floatx4 a, floatx4 b) {
    short8 o;
    o[0] = (short)f2bf(a.x); o[1] = (short)f2bf(a.y);
    o[2] = (short)f2bf(a.z); o[3] = (short)f2bf(a.w);
    o[4] = (short)f2bf(b.x); o[5] = (short)f2bf(b.y);
    o[6] = (short)f2bf(b.z); o[7] = (short)f2bf(b.w);
    return o;
}

__device__ __forceinline__ float dot4(floatx4 a, floatx4 b) {
    return a.x*b.x + a.y*b.y + a.z*b.z + a.w*b.w;
}

__device__ __forceinline__ float log_sigmoid(float x) {
    return fminf(x, 0.f) - __logf(1.f + __expf(-fabsf(x)));
}

// Gather + convert noise rows to bf16, TRANSPOSED chunk-major (R8 win):
// element (k, d) at nBT[(d>>5)*DT_STRIDE + k*32 + (d&31)]. Block 0 also
// zeroes out[64] for nce_main's atomic accumulation. IDEMPOTENT.
__global__ void prep_noise(const float* __restrict__ emb_w,
                           const float* __restrict__ emb_b,
                           const float* __restrict__ lpn,
                           const int* __restrict__ ns,
                           unsigned short* __restrict__ nBT,
                           float* __restrict__ nAdj,
                           float* __restrict__ out) {
    int k = blockIdx.x;     // 0..111
    int t = threadIdx.x;    // 0..127; d = t*4 .. t*4+3
    size_t off = (size_t)(t >> 3) * DT_STRIDE + k * 32 + (t & 7) * 4;
    if (k < Kq) {
        int row = ns[k];
        floatx4 v = ((const floatx4*)(emb_w + (size_t)row * Dq))[t];
        ushort4v o;
        o.x = f2bf(v.x); o.y = f2bf(v.y); o.z = f2bf(v.z); o.w = f2bf(v.w);
        *(ushort4v*)(nBT + off) = o;
        if (t == 0) nAdj[k] = emb_b[row] - NORM_TERM - lpn[row] - LOGK;
    } else {
        ushort4v z; z.x = 0; z.y = 0; z.z = 0; z.w = 0;
        *(ushort4v*)(nBT + off) = z;
        if (t == 0) nAdj[k] = 0.f;
    }
    if (k == 0 && t < 64) out[t] = 0.f;
}

// R18 structure (best, 25.7us): deferred target-dot reduction, staging is
// pure independent loads+stores; wave w<7: noise k-tile w vs both M-halves;
// wave 7: deferred tpart reduction + target epilogue; per-block atomic.
__global__ __launch_bounds__(512, 4) void nce_main(
    const float* __restrict__ input,     // [16384][512]
    const float* __restrict__ emb_w,     // [V][512]
    const float* __restrict__ emb_b,     // [V]
    const float* __restrict__ lpn,       // [V]
    const int* __restrict__ target,      // [16384]
    const unsigned short* __restrict__ nBT,  // noise, chunk-major bf16
    const float* __restrict__ nAdj,          // [112]
    float* __restrict__ out)                 // [64] accumulated
{
    __shared__ unsigned short A_lds[32 * 512];  // byte: row*1024 + (2c ^ ((row&7)<<4))
    __shared__ float tpart[32][65];             // padded: stride 65 breaks conflicts
    __shared__ float blocksum[8];

    int tid  = threadIdx.x;
    int lane = tid & 63;
    int w    = tid >> 6;            // 0..7
    int pos0 = (int)blockIdx.x * 32;
    int r16  = lane & 15;
    int g4   = lane >> 4;

    // ---- Stage: 4 rows/wave; pure loads + stores, NO reductions ----
#pragma unroll
    for (int j = 0; j < 4; ++j) {
        int row = w * 4 + j;                         // 0..31
        const float* src = input + (size_t)(pos0 + row) * Dq + lane * 8;
        int tg = target[pos0 + row];                 // wave-uniform -> scalar
        const float* tsrc = emb_w + (size_t)tg * Dq + lane * 8;
        floatx4 x0 = *(const floatx4*)(src);
        floatx4 x1 = *(const floatx4*)(src + 4);
        floatx4 t0 = *(const floatx4*)(tsrc);
        floatx4 t1 = *(const floatx4*)(tsrc + 4);
        tpart[row][lane] = dot4(x0, t0) + dot4(x1, t1);
        char* base = (char*)A_lds + row * 1024;
        *(ushort8v*)(base + ((lane * 16) ^ ((row & 7) << 4))) = (ushort8v)cvt8(x0, x1);
    }
    __syncthreads();

    float contrib = 0.f;

    if (w < 7) {
        // ---- Noise k-tile w vs BOTH M-tiles: 1 B-burst -> 2 MFMAs ----
        const char* a0base = (const char*)A_lds + r16 * 1024;          // rows 0-15
        const char* a1base = a0base + 16 * 1024;                       // rows 16-31
        int asw = (r16 & 7) << 4;   // same swizzle for row and row+16
        const unsigned short* p = nBT + (size_t)w * 512 + r16 * 32 + g4 * 8;
        floatx4 acc0 = {0.f, 0.f, 0.f, 0.f};
        floatx4 acc1 = {0.f, 0.f, 0.f, 0.f};
#pragma unroll
        for (int dt = 0; dt < 16; ++dt) {
            int aoff = (dt * 64 + g4 * 16) ^ asw;
            short8 a0 = *(const short8*)(a0base + aoff);
            short8 a1 = *(const short8*)(a1base + aoff);
            short8 f  = *(const short8*)(p + (size_t)dt * DT_STRIDE);
            acc0 = __builtin_amdgcn_mfma_f32_16x16x32_bf16(a0, f, acc0, 0, 0, 0);
            acc1 = __builtin_amdgcn_mfma_f32_16x16x32_bf16(a1, f, acc1, 0, 0, 0);
        }
        int k = w * 16 + r16;
        if (k < Kq) {
            float adj = nAdj[k];
#pragma unroll
            for (int r = 0; r < 4; ++r) {
                contrib += log_sigmoid(-(acc0[r] + adj));
                contrib += log_sigmoid(-(acc1[r] + adj));
            }
        }
    } else {
        // ---- Deferred target reduction: pos p = lane&31, half = lane>>5 ----
        int p32 = lane & 31;
        int hf  = lane >> 5;
        float s = 0.f;
#pragma unroll
        for (int i = 0; i < 32; ++i)
            s += tpart[p32][hf * 32 + i];
        s += __shfl_xor(s, 32);                      // lanes 0..31: full dot
        if (hf == 0) {
            int tg = target[pos0 + p32];
            float xt = s + emb_b[tg] - NORM_TERM - lpn[tg] - LOGK;
            contrib += log_sigmoid(xt);
        }
    }

#pragma unroll
    for (int off = 32; off >= 1; off >>= 1)
        contrib += __shfl_xor(contrib, off);
    if (lane == 0) blocksum[w] = contrib;
    __syncthreads();

    // ---- One atomic per block (8 per out address, 512 total) ----
    if (tid == 0) {
        float s = 0.f;
#pragma unroll
        for (int i = 0; i < 8; ++i) s += blocksum[i];
        atomicAdd(&out[blockIdx.x >> 3], s);         // batch = pos0/256
    }
}

extern "C" void kernel_launch(void* const* d_in, const int* in_sizes, int n_in,
                              void* d_out, int out_size, void* d_ws, size_t ws_size,
                              hipStream_t stream) {
    const float* input = (const float*)d_in[0];
    const float* emb_w = (const float*)d_in[1];
    const float* emb_b = (const float*)d_in[2];
    const float* lpn   = (const float*)d_in[3];
    const int*   tgt   = (const int*)d_in[4];
    const int*   ns    = (const int*)d_in[5];
    float* out = (float*)d_out;

    // ws layout: [0,114688) nBT bf16; [114688,115200) nAdj(+pad).
    unsigned short* nBT = (unsigned short*)d_ws;
    float* nAdj         = (float*)((char*)d_ws + (size_t)KP * Dq * 2);

    // MEASUREMENT: prep launched TWICE (idempotent; both precede main).
    // dur - 25.7 ~= prep + one node edge.
    prep_noise<<<KP, 128, 0, stream>>>(emb_w, emb_b, lpn, ns, nBT, nAdj, out);
    prep_noise<<<KP, 128, 0, stream>>>(emb_w, emb_b, lpn, ns, nBT, nAdj, out);
    nce_main<<<NBLK, 512, 0, stream>>>(input, emb_w, emb_b, lpn, tgt,
                                       nBT, nAdj, out);
}

// Round 20
// 25.475 us; speedup vs baseline: 1.0951x; 1.0951x over previous
//
#include <hip/hip_runtime.h>
#include <math.h>

// Problem constants
#define Dq 512
#define Vq 50257
#define Kq 100
#define KP 112              // K padded to 7*16
#define NORM_TERM 10.8249051f   // log(50257)
#define LOGK 4.6051702f         // log(100)
#define NBLK 512            // 16384 positions / 32 per block
#define DT_STRIDE 3584      // nBT: KP*32 elems per d-chunk slab (7KB, non-pow2)

typedef __attribute__((ext_vector_type(8))) short short8;
typedef __attribute__((ext_vector_type(4))) float floatx4;
typedef __attribute__((ext_vector_type(4))) unsigned short ushort4v;
typedef __attribute__((ext_vector_type(8))) unsigned short ushort8v;

__device__ __forceinline__ unsigned short f2bf(float f) {
    union { float f; unsigned u; } v; v.f = f;
    unsigned r = v.u + 0x7FFFu + ((v.u >> 16) & 1u);   // RNE
    return (unsigned short)(r >> 16);
}

__device__ __forceinline__ short8 cvt8(floatx4 a, floatx4 b) {
    short8 o;
    o[0] = (short)f2bf(a.x); o[1] = (short)f2bf(a.y);
    o[2] = (short)f2bf(a.z); o[3] = (short)f2bf(a.w);
    o[4] = (short)f2bf(b.x); o[5] = (short)f2bf(b.y);
    o[6] = (short)f2bf(b.z); o[7] = (short)f2bf(b.w);
    return o;
}

__device__ __forceinline__ float dot4(floatx4 a, floatx4 b) {
    return a.x*b.x + a.y*b.y + a.z*b.z + a.w*b.w;
}

__device__ __forceinline__ float log_sigmoid(float x) {
    return fminf(x, 0.f) - __logf(1.f + __expf(-fabsf(x)));
}

// Gather + convert noise rows to bf16, TRANSPOSED chunk-major (R8 win):
// element (k, d) at nBT[(d>>5)*DT_STRIDE + k*32 + (d&31)]. Block 0 also
// zeroes out[64] for nce_main's atomic accumulation.
__global__ void prep_noise(const float* __restrict__ emb_w,
                           const float* __restrict__ emb_b,
                           const float* __restrict__ lpn,
                           const int* __restrict__ ns,
                           unsigned short* __restrict__ nBT,
                           float* __restrict__ nAdj,
                           float* __restrict__ out) {
    int k = blockIdx.x;     // 0..111
    int t = threadIdx.x;    // 0..127; d = t*4 .. t*4+3
    size_t off = (size_t)(t >> 3) * DT_STRIDE + k * 32 + (t & 7) * 4;
    if (k < Kq) {
        int row = ns[k];
        floatx4 v = ((const floatx4*)(emb_w + (size_t)row * Dq))[t];
        ushort4v o;
        o.x = f2bf(v.x); o.y = f2bf(v.y); o.z = f2bf(v.z); o.w = f2bf(v.w);
        *(ushort4v*)(nBT + off) = o;
        if (t == 0) nAdj[k] = emb_b[row] - NORM_TERM - lpn[row] - LOGK;
    } else {
        ushort4v z; z.x = 0; z.y = 0; z.z = 0; z.w = 0;
        *(ushort4v*)(nBT + off) = z;
        if (t == 0) nAdj[k] = 0.f;
    }
    if (k == 0 && t < 64) out[t] = 0.f;
}

// Best structure (R18, 25.7us): block = 8 waves = 32 positions.
// Staging: pure independent loads + LDS stores (NO shfl chains — the R18
// win: keeps all loads in flight); per-lane target-dot partials to padded
// tpart. Barrier. Waves 0-6: noise k-tile w vs both M-halves (transposed
// nBT 1KB bursts — the R8 win). Wave 7: deferred target reduction +
// epilogue. Per-block atomic into out[batch].
__global__ __launch_bounds__(512, 4) void nce_main(
    const float* __restrict__ input,     // [16384][512]
    const float* __restrict__ emb_w,     // [V][512]
    const float* __restrict__ emb_b,     // [V]
    const float* __restrict__ lpn,       // [V]
    const int* __restrict__ target,      // [16384]
    const unsigned short* __restrict__ nBT,  // noise, chunk-major bf16
    const float* __restrict__ nAdj,          // [112]
    float* __restrict__ out)                 // [64] accumulated
{
    __shared__ unsigned short A_lds[32 * 512];  // byte: row*1024 + (2c ^ ((row&7)<<4))
    __shared__ float tpart[32][65];             // padded: stride 65 breaks conflicts
    __shared__ float blocksum[8];

    int tid  = threadIdx.x;
    int lane = tid & 63;
    int w    = tid >> 6;            // 0..7
    int pos0 = (int)blockIdx.x * 32;
    int r16  = lane & 15;
    int g4   = lane >> 4;

    // ---- Stage: 4 rows/wave; pure loads + stores, NO reductions ----
#pragma unroll
    for (int j = 0; j < 4; ++j) {
        int row = w * 4 + j;                         // 0..31
        const float* src = input + (size_t)(pos0 + row) * Dq + lane * 8;
        int tg = target[pos0 + row];                 // wave-uniform -> scalar
        const float* tsrc = emb_w + (size_t)tg * Dq + lane * 8;
        floatx4 x0 = *(const floatx4*)(src);
        floatx4 x1 = *(const floatx4*)(src + 4);
        floatx4 t0 = *(const floatx4*)(tsrc);
        floatx4 t1 = *(const floatx4*)(tsrc + 4);
        tpart[row][lane] = dot4(x0, t0) + dot4(x1, t1);
        char* base = (char*)A_lds + row * 1024;
        *(ushort8v*)(base + ((lane * 16) ^ ((row & 7) << 4))) = (ushort8v)cvt8(x0, x1);
    }
    __syncthreads();

    float contrib = 0.f;

    if (w < 7) {
        // ---- Noise k-tile w vs BOTH M-tiles: 1 B-burst -> 2 MFMAs ----
        const char* a0base = (const char*)A_lds + r16 * 1024;          // rows 0-15
        const char* a1base = a0base + 16 * 1024;                       // rows 16-31
        int asw = (r16 & 7) << 4;   // same swizzle for row and row+16
        const unsigned short* p = nBT + (size_t)w * 512 + r16 * 32 + g4 * 8;
        floatx4 acc0 = {0.f, 0.f, 0.f, 0.f};
        floatx4 acc1 = {0.f, 0.f, 0.f, 0.f};
#pragma unroll
        for (int dt = 0; dt < 16; ++dt) {
            int aoff = (dt * 64 + g4 * 16) ^ asw;
            short8 a0 = *(const short8*)(a0base + aoff);
            short8 a1 = *(const short8*)(a1base + aoff);
            short8 f  = *(const short8*)(p + (size_t)dt * DT_STRIDE);
            acc0 = __builtin_amdgcn_mfma_f32_16x16x32_bf16(a0, f, acc0, 0, 0, 0);
            acc1 = __builtin_amdgcn_mfma_f32_16x16x32_bf16(a1, f, acc1, 0, 0, 0);
        }
        int k = w * 16 + r16;
        if (k < Kq) {
            float adj = nAdj[k];
#pragma unroll
            for (int r = 0; r < 4; ++r) {
                contrib += log_sigmoid(-(acc0[r] + adj));
                contrib += log_sigmoid(-(acc1[r] + adj));
            }
        }
    } else {
        // ---- Deferred target reduction: pos p = lane&31, half = lane>>5 ----
        int p32 = lane & 31;
        int hf  = lane >> 5;
        float s = 0.f;
#pragma unroll
        for (int i = 0; i < 32; ++i)
            s += tpart[p32][hf * 32 + i];
        s += __shfl_xor(s, 32);                      // lanes 0..31: full dot
        if (hf == 0) {
            int tg = target[pos0 + p32];
            float xt = s + emb_b[tg] - NORM_TERM - lpn[tg] - LOGK;
            contrib += log_sigmoid(xt);
        }
    }

#pragma unroll
    for (int off = 32; off >= 1; off >>= 1)
        contrib += __shfl_xor(contrib, off);
    if (lane == 0) blocksum[w] = contrib;
    __syncthreads();

    // ---- One atomic per block (8 per out address, 512 total) ----
    if (tid == 0) {
        float s = 0.f;
#pragma unroll
        for (int i = 0; i < 8; ++i) s += blocksum[i];
        atomicAdd(&out[blockIdx.x >> 3], s);         // batch = pos0/256
    }
}

extern "C" void kernel_launch(void* const* d_in, const int* in_sizes, int n_in,
                              void* d_out, int out_size, void* d_ws, size_t ws_size,
                              hipStream_t stream) {
    const float* input = (const float*)d_in[0];
    const float* emb_w = (const float*)d_in[1];
    const float* emb_b = (const float*)d_in[2];
    const float* lpn   = (const float*)d_in[3];
    const int*   tgt   = (const int*)d_in[4];
    const int*   ns    = (const int*)d_in[5];
    float* out = (float*)d_out;

    // ws layout: [0,114688) nBT bf16; [114688,115200) nAdj(+pad).
    unsigned short* nBT = (unsigned short*)d_ws;
    float* nAdj         = (float*)((char*)d_ws + (size_t)KP * Dq * 2);

    prep_noise<<<KP, 128, 0, stream>>>(emb_w, emb_b, lpn, ns, nBT, nAdj, out);
    nce_main<<<NBLK, 512, 0, stream>>>(input, emb_w, emb_b, lpn, tgt,
                                       nBT, nAdj, out);
}